// Round 7
// baseline (730.051 us; speedup 1.0000x reference)
//
#include <hip/hip_runtime.h>
#include <stdint.h>

// SparseConv3d: x [4,64,64,64,64] f32, w [64,64,3,3,3] f32 -> out [4,64,64,64,64] f32
// out = conv3d_SAME(x, w) masked to voxels where any input channel is nonzero.
// v8: LDS-FREE gather-GEMM. A-fragments and B-fragments load global->VGPR
//   directly (per-lane fragment addressing; no global_load_lds, no ds_read,
//   no s_barrier, no inline asm). 3-slot register rotation, 2-tap prefetch
//   depth; the compiler's own minimal vmcnt before each MFMA implements the
//   counted-wait pipeline. A rows are wave-private (zero reuse) so LDS staging
//   was pure latency; B (110KB) is L1/L2-hot chip-wide.
//   Keeps: compact-matrix output (full-line writes), XCD bijective tile
//   swizzle, halo-padded xt (tap addressing = base + compile-time delta),
//   register-transpose finalize.

#define R3 262144           // 64^3 spatial per batch
#define NVOX (4 * R3)       // 1048576 voxels total
#define P  66
#define PS (66 * 66)        // 4356
#define PB (66 * 66 * 66)   // 287496 padded voxels per batch
#define WSW_ELEMS (27 * 2 * 4 * 64 * 8)   // 110592 swizzled weight bf16
#define CAP (NVOX / 2)      // compact-matrix capacity (input is ~30% dense)

typedef __attribute__((ext_vector_type(4))) float f32x4;
typedef __attribute__((ext_vector_type(8))) short short8;

static __device__ inline unsigned short f2bf(float f) {
    union { float f; unsigned u; } v; v.f = f;
    unsigned u = v.u;
    return (unsigned short)((u + 0x7fffu + ((u >> 16) & 1u)) >> 16);  // RNE
}

// ---- weight swizzle: B-fragment order for mfma_f32_16x16x32_bf16 ----
// B[k][n]: lane holds B[k=(lane>>4)*8+j][n=lane&15], j=0..7 contiguous (16B/lane).
// layout: [tap 27][kc 2][nt 4][lane 64][j 8] -> per-tap slice is 8192B contiguous.
__global__ void wprep(const float* __restrict__ w, unsigned short* __restrict__ wsw) {
    int e = blockIdx.x * 256 + threadIdx.x;
    if (e >= WSW_ELEMS) return;
    int j    = e & 7;
    int lane = (e >> 3) & 63;
    int nt   = (e >> 9) & 3;
    int kc   = (e >> 11) & 1;
    int tap  = e >> 12;                       // kz*9+ky*3+kx
    int co = nt * 16 + (lane & 15);
    int ci = kc * 32 + ((lane >> 4) * 8) + j;
    wsw[e] = f2bf(w[(co * 64 + ci) * 27 + tap]);
}

// ---- zero the halo shell of padded xt (13 MB of writes) ----
__global__ void __launch_bounds__(256) halo_zero(uint4* __restrict__ xt4) {
    int p = blockIdx.x * 256 + threadIdx.x;
    if (p >= 4 * PB) return;
    int b = p / PB;
    int rp = p - b * PB;
    int z = rp / PS; rp -= z * PS;
    int y = rp / P;  int xx = rp - y * P;
    if (z == 0 || z == 65 || y == 0 || y == 65 || xx == 0 || xx == 65) {
        uint4 zz = {0, 0, 0, 0};
        uint4* d = xt4 + (size_t)p * 8;   // 128B per voxel
#pragma unroll
        for (int k = 0; k < 8; ++k) d[k] = zz;
    }
}

// ---- pass 1: transpose x -> channels-last bf16 into PADDED xt, mask + compaction ----
// Also writes pos[v] = compact index (or -1) for the finalize scatter.
__global__ void __launch_bounds__(256) xprep(const float* __restrict__ x,
                                             unsigned int* __restrict__ xt_u32,
                                             int* __restrict__ list,
                                             int* __restrict__ pos,
                                             int* __restrict__ count) {
    __shared__ unsigned int lds[256 * 36];    // [voxel 256][ci-pair 32], pad->36 (16B-aligned rows)
    __shared__ unsigned int wcnt[4], wbase[4], bbase;
    int t = threadIdx.x;
    int v = blockIdx.x * 256 + t;             // blocks never straddle batch (256 | 262144)
    int b = v >> 18;
    int s = v & (R3 - 1);
    const float* xb = x + (size_t)b * (64 * R3) + s;
    bool active = false;
    unsigned int pk[32];
#pragma unroll
    for (int c2 = 0; c2 < 32; ++c2) {
        float f0 = xb[(size_t)(2 * c2) * R3];
        float f1 = xb[(size_t)(2 * c2 + 1) * R3];
        active |= (f0 != 0.f) | (f1 != 0.f);
        pk[c2] = (unsigned)f2bf(f0) | ((unsigned)f2bf(f1) << 16);
    }
#pragma unroll
    for (int k = 0; k < 8; ++k) {
        uint4 q = { pk[4 * k], pk[4 * k + 1], pk[4 * k + 2], pk[4 * k + 3] };
        *(uint4*)&lds[t * 36 + 4 * k] = q;
    }
    __syncthreads();
    // coalesced write-out into padded layout: block = 4 x-rows at (z0, y0..y0+3)
    int s0 = (blockIdx.x * 256) & (R3 - 1);
    int z0 = s0 >> 12;
    int y0 = (s0 >> 6) & 63;
    size_t rowbase = ((size_t)b * PB + (size_t)(z0 + 1) * PS + (size_t)(y0 + 1) * P + 1) * 32;
#pragma unroll
    for (int i = 0; i < 8; ++i) {
        int g4 = i * 256 + t;                 // uint4 index 0..2047
        int vox = g4 >> 3;                    // voxel 0..255 within block
        int col = (g4 & 7) * 4;               // u32 col within voxel
        uint4 val = *(const uint4*)&lds[vox * 36 + col];
        int r = vox >> 6;                     // x-row 0..3
        int xc = vox & 63;
        *(uint4*)&xt_u32[rowbase + (size_t)r * (P * 32) + (size_t)xc * 32 + col] = val;
    }
    // compaction
    int lane = t & 63, w = t >> 6;
    unsigned long long bal = __ballot(active);
    if (lane == 0) wcnt[w] = (unsigned)__popcll(bal);
    __syncthreads();
    if (t == 0) {
        unsigned tot = 0;
        for (int i = 0; i < 4; ++i) { wbase[i] = tot; tot += wcnt[i]; }
        bbase = (unsigned)atomicAdd(count, (int)tot);
    }
    __syncthreads();
    int p = -1;
    if (active) {
        unsigned pp = bbase + wbase[w] + (unsigned)__popcll(bal & ((1ULL << lane) - 1ULL));
        list[pp] = v;
        p = (int)pp;
    }
    pos[v] = p;
}

// ---- pass 2: LDS-free gather-GEMM, 32 voxels x 64 co per WAVE (4 waves/block) ----
// Per tap t the wave issues 12 VMEM loads (4 A-fragment dwordx4 + 8 B dwordx4)
// two taps ahead into a 3-slot register ring, then runs 16 MFMAs on tap t.
// The compiler's auto-inserted vmcnt before MFMA(t) retires exactly the loads
// issued at body t-2 -> counted-wait pipeline, no asm, no barriers, no LDS.
#define ALOAD(tp, sl) do { if ((tp) < 27) {                                         \
    const int dz_ = (tp) / 9 - 1, dy_ = ((tp) / 3) % 3 - 1, dx_ = (tp) % 3 - 1;     \
    const int dlt_ = (dz_ * PS + dy_ * P + dx_) * 128;                              \
    _Pragma("unroll")                                                               \
    for (int m_ = 0; m_ < 2; ++m_)                                                  \
    _Pragma("unroll")                                                               \
    for (int kc_ = 0; kc_ < 2; ++kc_)                                               \
        a[sl][m_][kc_] = *(const short8*)(xt +                                      \
            (size_t)(voffA[m_] + (unsigned)(dlt_ + kc_ * 64)));                     \
} } while (0)

#define BLOAD(tp, sl) do { if ((tp) < 27) {                                         \
    _Pragma("unroll")                                                               \
    for (int j_ = 0; j_ < 8; ++j_)                                                  \
        b[sl][j_] = *(const short8*)(wswb + (size_t)((tp) * 8192 + j_ * 1024)       \
                                     + voffB);                                      \
} } while (0)

__global__ void __launch_bounds__(256, 2) sconv_gemm(const unsigned char* __restrict__ xt,
                                                     const unsigned char* __restrict__ wswb,
                                                     const int* __restrict__ list,
                                                     const int* __restrict__ count_p,
                                                     float* __restrict__ out,
                                                     float* __restrict__ compact,
                                                     int use_compact) {
    int count = *count_p;
    int nt_act = (count + 127) >> 7;          // active tiles (M=128/block)
    int bid = blockIdx.x;
    if (bid >= nt_act) return;
    // bijective XCD swizzle over active tiles (m204): consecutive spatial tiles
    // share ~2/3 of their gather halo -> keep them on one XCD's L2.
    int qd = nt_act >> 3, rd = nt_act & 7;
    int xcd = bid & 7, ixx = bid >> 3;
    int tile = (xcd < rd ? xcd * (qd + 1) : rd * (qd + 1) + (xcd - rd) * qd) + ixx;
    int t = threadIdx.x;
    int lane = t & 63, w = t >> 6;            // 4 independent waves
    int base = tile * 128 + w * 32;           // wave owns rows base..base+31
    int cl = lane & 15;
    int hi16 = (lane >> 4) * 16;              // A-fragment k-segment per lane

    // Per-lane A row offsets into padded xt (32-bit; min row offset 566144
    // >= |min tap delta| 566144, so voffA+delta never goes negative).
    unsigned voffA[2];
#pragma unroll
    for (int m = 0; m < 2; ++m) {
        int gi = base + m * 16 + cl;
        int vid = (gi < count) ? list[gi] : 0;
        int bb = vid >> 18, sp = vid & (R3 - 1);
        int vz = sp >> 12, vy = (sp >> 6) & 63, vx = sp & 63;
        voffA[m] = (unsigned)((bb * PB + (vz + 1) * PS + (vy + 1) * P + (vx + 1)) * 128)
                   + (unsigned)hi16;
    }
    unsigned voffB = (unsigned)(lane * 16);

    f32x4 acc[2][4] = {};
    short8 a[3][2][2];                        // [slot][m][kc] — all indices static
    short8 b[3][8];                           // [slot][kc*4+n]

    // prologue: taps 0 and 1 in flight (24 loads)
    BLOAD(0, 0); ALOAD(0, 0);
    BLOAD(1, 1); ALOAD(1, 1);
#pragma unroll
    for (int tp = 0; tp < 27; ++tp) {
        const int sl = tp % 3;
        // issue tap t+2 (slot (t+2)%3: neither t's nor t+1's -> no WAR)
        BLOAD(tp + 2, (tp + 2) % 3);
        ALOAD(tp + 2, (tp + 2) % 3);
        // MFMA(t): compiler-inserted vmcnt retires exactly tap-t's 12 loads
#pragma unroll
        for (int n = 0; n < 4; ++n) {
            acc[0][n] = __builtin_amdgcn_mfma_f32_16x16x32_bf16(a[sl][0][0], b[sl][n], acc[0][n], 0, 0, 0);
            acc[1][n] = __builtin_amdgcn_mfma_f32_16x16x32_bf16(a[sl][1][0], b[sl][n], acc[1][n], 0, 0, 0);
        }
#pragma unroll
        for (int n = 0; n < 4; ++n) {
            acc[0][n] = __builtin_amdgcn_mfma_f32_16x16x32_bf16(a[sl][0][1], b[sl][4 + n], acc[0][n], 0, 0, 0);
            acc[1][n] = __builtin_amdgcn_mfma_f32_16x16x32_bf16(a[sl][1][1], b[sl][4 + n], acc[1][n], 0, 0, 0);
        }
    }

    // epilogue: D[row=(lane>>4)*4+reg][col=lane&15] (m89-verified layout)
    int q = lane >> 4;
    if (use_compact) {
        // dense compact[idx][64]: full-line coalesced writes
#pragma unroll
        for (int m = 0; m < 2; ++m) {
#pragma unroll
            for (int rg = 0; rg < 4; ++rg) {
                int row = m * 16 + q * 4 + rg;            // 0..31 within wave
                int gi = base + row;
                if (gi < count && gi < CAP) {
#pragma unroll
                    for (int n = 0; n < 4; ++n)
                        compact[(size_t)gi * 64 + n * 16 + cl] = acc[m][n][rg];
                }
            }
        }
    } else {
#pragma unroll
        for (int m = 0; m < 2; ++m) {
#pragma unroll
            for (int rg = 0; rg < 4; ++rg) {
                int row = m * 16 + q * 4 + rg;
                int gi = base + row;
                if (gi < count) {
                    int vv = list[gi];
                    int bb2 = vv >> 18;
                    int sp = vv & (R3 - 1);
                    float* op = out + (size_t)(bb2 * 64 + cl) * R3 + sp;
#pragma unroll
                    for (int n = 0; n < 4; ++n)
                        op[(size_t)(n * 16) * R3] = acc[m][n][rg];
                }
            }
        }
    }
}

// ---- pass 3: compact -> dense NCDHW (writes zeros for inactive; replaces memset) ----
// Register transpose: thread t owns voxel vb+t; reads its full 256B compact row
// (every fetched line fully consumed), then 64 coalesced per-co stores.
__global__ void __launch_bounds__(256) finalize(const uint4* __restrict__ compact4,
                                                const int* __restrict__ pos,
                                                float* __restrict__ out) {
    int t = threadIdx.x;
    int vb = blockIdx.x * 256;                // 256 consecutive voxels (never straddle batch)
    int b = vb >> 18;
    int sp0 = vb & (R3 - 1);
    int q = pos[vb + t];
    bool act = (unsigned)q < (unsigned)CAP;
    const uint4* src = compact4 + (size_t)(act ? q : 0) * 16;
    uint4 r[16];
#pragma unroll
    for (int s = 0; s < 16; ++s) {
        uint4 v = {0, 0, 0, 0};
        if (act) v = src[s];
        r[s] = v;
    }
    const float* rf = (const float*)r;
    float* ob = out + (size_t)b * 64 * R3 + sp0 + t;
#pragma unroll
    for (int co = 0; co < 64; ++co)
        ob[(size_t)co * R3] = rf[co];         // co compile-time (rule 20): stays in regs
}

// ---- fallback (ws too small): dense fp32 direct conv, one (b,co,z,y) row per block ----
__global__ void __launch_bounds__(64) fallback_conv(const float* __restrict__ x,
                                                    const float* __restrict__ wt,
                                                    float* __restrict__ out) {
    __shared__ float rowb[66];
    int bid = blockIdx.x;
    int y = bid & 63, z = (bid >> 6) & 63, co = (bid >> 12) & 63, b = bid >> 18;
    int t = threadIdx.x;
    float acc = 0.f;
    bool active = false;
    for (int ci = 0; ci < 64; ++ci) {
        const float* xp = x + ((size_t)(b * 64 + ci)) * R3;
        const float* wp = wt + ((size_t)(co * 64 + ci)) * 27;
        for (int dz = -1; dz <= 1; ++dz) {
            int nz = z + dz;
            bool okz = (unsigned)nz < 64u;
            for (int dy = -1; dy <= 1; ++dy) {
                int ny = y + dy;
                bool ok = okz && ((unsigned)ny < 64u);
                float v = ok ? xp[nz * 4096 + ny * 64 + t] : 0.f;
                rowb[t + 1] = v;
                if (t == 0) { rowb[0] = 0.f; rowb[65] = 0.f; }
                __syncthreads();
                if (dz == 0 && dy == 0) active |= (rowb[t + 1] != 0.f);
                const float* wq = wp + (dz + 1) * 9 + (dy + 1) * 3;
                acc += rowb[t] * wq[0] + rowb[t + 1] * wq[1] + rowb[t + 2] * wq[2];
                __syncthreads();
            }
        }
    }
    out[((size_t)(b * 64 + co)) * R3 + z * 4096 + y * 64 + t] = active ? acc : 0.f;
}

extern "C" void kernel_launch(void* const* d_in, const int* in_sizes, int n_in,
                              void* d_out, int out_size, void* d_ws, size_t ws_size,
                              hipStream_t stream) {
    const float* x = (const float*)d_in[0];
    const float* w = (const float*)d_in[1];
    float* out = (float*)d_out;

    const size_t XT_BYTES = (size_t)4 * PB * 128;             // 147.2 MB padded bf16 channels-last
    const size_t LIST_OFF = XT_BYTES;                         // 4 MB int list
    const size_t POS_OFF  = LIST_OFF + (size_t)NVOX * 4;      // 4 MB int pos
    const size_t WSW_OFF  = POS_OFF + (size_t)NVOX * 4;
    const size_t CNT_OFF  = WSW_OFF + (size_t)WSW_ELEMS * 2;
    const size_t CMP_OFF  = (CNT_OFF + 256 + 255) & ~(size_t)255;
    const size_t NEED_S   = CMP_OFF;                          // scatter path (~156 MB)
    const size_t NEED_C   = CMP_OFF + (size_t)CAP * 64 * 4;   // compact path (~290 MB)

    if (ws_size < NEED_S) {
        fallback_conv<<<NVOX, 64, 0, stream>>>(x, w, out);
        return;
    }

    unsigned int*   xt   = (unsigned int*)d_ws;
    int*            list = (int*)((char*)d_ws + LIST_OFF);
    int*            pos  = (int*)((char*)d_ws + POS_OFF);
    unsigned short* wsw  = (unsigned short*)((char*)d_ws + WSW_OFF);
    int*            cnt  = (int*)((char*)d_ws + CNT_OFF);
    float*          cmp  = (float*)((char*)d_ws + CMP_OFF);
    int use_compact = (ws_size >= NEED_C) ? 1 : 0;

    hipMemsetAsync(cnt, 0, sizeof(int), stream);
    if (!use_compact)
        hipMemsetAsync(d_out, 0, (size_t)out_size * sizeof(float), stream);
    wprep<<<WSW_ELEMS / 256, 256, 0, stream>>>(w, wsw);
    halo_zero<<<(4 * PB + 255) / 256, 256, 0, stream>>>((uint4*)d_ws);
    xprep<<<NVOX / 256, 256, 0, stream>>>(x, xt, list, pos, cnt);
    sconv_gemm<<<NVOX / 128, 256, 0, stream>>>((const unsigned char*)xt,
                                               (const unsigned char*)wsw, list, cnt,
                                               out, cmp, use_compact);
    if (use_compact)
        finalize<<<NVOX / 256, 256, 0, stream>>>((const uint4*)cmp, pos, out);
}

// Round 8
// 648.555 us; speedup vs baseline: 1.1257x; 1.1257x over previous
//
#include <hip/hip_runtime.h>
#include <stdint.h>

// SparseConv3d: x [4,64,64,64,64] f32, w [64,64,3,3,3] f32 -> out [4,64,64,64,64] f32
// out = conv3d_SAME(x, w) masked to voxels where any input channel is nonzero.
// v9 = v6 (best measured: 650.8us) + wprep/halo_zero fused into one launch.
//   - sconv: 256-voxel x 64-co tiles, 512 threads (8 waves), A/B double-buffer,
//     raw s_barrier + counted waits, LDS exactly 80 KB -> 2 blocks/CU.
//     (v5 3-buf, v7 barrier-free LDS, v8 LDS-free reg-ring all measured worse.)
//   - compact-matrix output (full-line writes) + register-transpose finalize.
//   - XCD bijective tile swizzle, T21 pre-swizzled A staging, halo-padded xt.

#define R3 262144           // 64^3 spatial per batch
#define NVOX (4 * R3)       // 1048576 voxels total
#define P  66
#define PS (66 * 66)        // 4356
#define PB (66 * 66 * 66)   // 287496 padded voxels per batch
#define WSW_ELEMS (27 * 2 * 4 * 64 * 8)   // 110592 swizzled weight bf16
#define CAP (NVOX / 2)      // compact-matrix capacity (input is ~30% dense)

typedef __attribute__((ext_vector_type(4))) float f32x4;
typedef __attribute__((ext_vector_type(8))) short short8;

static __device__ inline unsigned short f2bf(float f) {
    union { float f; unsigned u; } v; v.f = f;
    unsigned u = v.u;
    return (unsigned short)((u + 0x7fffu + ((u >> 16) & 1u)) >> 16);  // RNE
}

static __device__ __forceinline__ void gload16(const void* g, void* l) {
    __builtin_amdgcn_global_load_lds(
        (const __attribute__((address_space(1))) unsigned int*)g,
        (__attribute__((address_space(3))) unsigned int*)l, 16, 0, 0);
}

// ---- fused small-prep: weight swizzle (first 432 blocks) + xt halo zero ----
// wsw layout: [tap 27][kc 2][nt 4][lane 64][j 8]; B[k][n] fragment order for
// mfma_f32_16x16x32_bf16 (lane holds B[k=(lane>>4)*8+j][n=lane&15]).
__global__ void __launch_bounds__(256) prep_misc(const float* __restrict__ w,
                                                 unsigned short* __restrict__ wsw,
                                                 uint4* __restrict__ xt4) {
    int idx = blockIdx.x * 256 + threadIdx.x;
    // --- halo shell zero (13 MB of writes), all blocks ---
    if (idx < 4 * PB) {
        int b = idx / PB;
        int rp = idx - b * PB;
        int z = rp / PS; rp -= z * PS;
        int y = rp / P;  int xx = rp - y * P;
        if (z == 0 || z == 65 || y == 0 || y == 65 || xx == 0 || xx == 65) {
            uint4 zz = {0, 0, 0, 0};
            uint4* d = xt4 + (size_t)idx * 8;   // 128B per voxel
#pragma unroll
            for (int k = 0; k < 8; ++k) d[k] = zz;
        }
    }
    // --- weight swizzle, first WSW_ELEMS/256 blocks (disjoint buffer) ---
    if (idx < WSW_ELEMS) {
        int e = idx;
        int j    = e & 7;
        int lane = (e >> 3) & 63;
        int nt   = (e >> 9) & 3;
        int kc   = (e >> 11) & 1;
        int tap  = e >> 12;                   // kz*9+ky*3+kx
        int co = nt * 16 + (lane & 15);
        int ci = kc * 32 + ((lane >> 4) * 8) + j;
        wsw[e] = f2bf(w[(co * 64 + ci) * 27 + tap]);
    }
}

// ---- pass 1: transpose x -> channels-last bf16 into PADDED xt, mask + compaction ----
// Also writes pos[v] = compact index (or -1) for the finalize scatter.
__global__ void __launch_bounds__(256) xprep(const float* __restrict__ x,
                                             unsigned int* __restrict__ xt_u32,
                                             int* __restrict__ list,
                                             int* __restrict__ pos,
                                             int* __restrict__ count) {
    __shared__ unsigned int lds[256 * 36];    // [voxel 256][ci-pair 32], pad->36 (16B-aligned rows)
    __shared__ unsigned int wcnt[4], wbase[4], bbase;
    int t = threadIdx.x;
    int v = blockIdx.x * 256 + t;             // blocks never straddle batch (256 | 262144)
    int b = v >> 18;
    int s = v & (R3 - 1);
    const float* xb = x + (size_t)b * (64 * R3) + s;
    bool active = false;
    unsigned int pk[32];
#pragma unroll
    for (int c2 = 0; c2 < 32; ++c2) {
        float f0 = xb[(size_t)(2 * c2) * R3];
        float f1 = xb[(size_t)(2 * c2 + 1) * R3];
        active |= (f0 != 0.f) | (f1 != 0.f);
        pk[c2] = (unsigned)f2bf(f0) | ((unsigned)f2bf(f1) << 16);
    }
#pragma unroll
    for (int k = 0; k < 8; ++k) {
        uint4 q = { pk[4 * k], pk[4 * k + 1], pk[4 * k + 2], pk[4 * k + 3] };
        *(uint4*)&lds[t * 36 + 4 * k] = q;
    }
    __syncthreads();
    // coalesced write-out into padded layout: block = 4 x-rows at (z0, y0..y0+3)
    int s0 = (blockIdx.x * 256) & (R3 - 1);
    int z0 = s0 >> 12;
    int y0 = (s0 >> 6) & 63;
    size_t rowbase = ((size_t)b * PB + (size_t)(z0 + 1) * PS + (size_t)(y0 + 1) * P + 1) * 32;
#pragma unroll
    for (int i = 0; i < 8; ++i) {
        int g4 = i * 256 + t;                 // uint4 index 0..2047
        int vox = g4 >> 3;                    // voxel 0..255 within block
        int col = (g4 & 7) * 4;               // u32 col within voxel
        uint4 val = *(const uint4*)&lds[vox * 36 + col];
        int r = vox >> 6;                     // x-row 0..3
        int xc = vox & 63;
        *(uint4*)&xt_u32[rowbase + (size_t)r * (P * 32) + (size_t)xc * 32 + col] = val;
    }
    // compaction
    int lane = t & 63, w = t >> 6;
    unsigned long long bal = __ballot(active);
    if (lane == 0) wcnt[w] = (unsigned)__popcll(bal);
    __syncthreads();
    if (t == 0) {
        unsigned tot = 0;
        for (int i = 0; i < 4; ++i) { wbase[i] = tot; tot += wcnt[i]; }
        bbase = (unsigned)atomicAdd(count, (int)tot);
    }
    __syncthreads();
    int p = -1;
    if (active) {
        unsigned pp = bbase + wbase[w] + (unsigned)__popcll(bal & ((1ULL << lane) - 1ULL));
        list[pp] = v;
        p = (int)pp;
    }
    pos[v] = p;
}

// ---- pass 2: gather-GEMM, 256 voxels x 64 co per block, 512 threads ----
// A LDS layout (per 32KB buffer): row r (0..255) occupies bytes [r*128, r*128+128),
// stored XOR-swizzled: source byte o of the voxel row lands at o ^ ((r&7)<<4).
// Staged via global_load_lds with PRE-SWIZZLED global source (T21), read with the
// same XOR -> bank-conflict-free ds_read_b128 despite the 128B row stride.
// Per tap per thread: 4 A-loads (dest t*16 + i*8192 = wave-uniform + lane*16) + 1 B-load.
#define STAGE(tap, buf) do {                                                       \
    const int dz_ = (tap) / 9 - 1, dy_ = ((tap) / 3) % 3 - 1, dx_ = (tap) % 3 - 1; \
    const ptrdiff_t dlt_ = (ptrdiff_t)(dz_ * PS + dy_ * P + dx_) * 128;            \
    _Pragma("unroll")                                                              \
    for (int i_ = 0; i_ < 4; ++i_)                                                 \
        gload16(asrc[i_] + dlt_, &Ab[buf][t * 16 + i_ * 8192]);                    \
    gload16(wswb + (size_t)(tap) * 8192 + t * 16, &Bb[buf][t * 16]);               \
} while (0)

__global__ void __launch_bounds__(512) sconv_gemm(const unsigned char* __restrict__ xt,
                                                  const unsigned char* __restrict__ wswb,
                                                  const int* __restrict__ list,
                                                  const int* __restrict__ count_p,
                                                  float* __restrict__ out,
                                                  float* __restrict__ compact,
                                                  int use_compact) {
    __shared__ __align__(16) unsigned char Ab[2][32768];  // 256 rows x 128B, dbuf
    __shared__ __align__(16) unsigned char Bb[2][8192];   // per-tap B slice, dbuf
    int count = *count_p;
    int nt_act = (count + 255) >> 8;          // active tiles
    int bid = blockIdx.x;
    if (bid >= nt_act) return;
    // bijective XCD swizzle over active tiles (m204): consecutive spatial tiles
    // share ~2/3 of their gather halo -> keep them on one XCD's L2.
    int qd = nt_act >> 3, rd = nt_act & 7;
    int xcd = bid & 7, ixx = bid >> 3;
    int tile = (xcd < rd ? xcd * (qd + 1) : rd * (qd + 1) + (xcd - rd) * qd) + ixx;
    int base = tile * 256;
    int t = threadIdx.x;

    // per-thread staging sources: 4 fixed rows r0+64i, fixed 16B segment seg.
    // list[] read direct from global: 8 threads share each element (L1 broadcast).
    const unsigned char* asrc[4];
    {
        int seg = t & 7;
        int r0 = t >> 3;                          // 0..63
        int off = (seg * 16) ^ ((r0 & 7) << 4);   // pre-swizzled source offset
#pragma unroll
        for (int i = 0; i < 4; ++i) {
            int gi = base + r0 + 64 * i;
            int vid = (gi < count) ? list[gi] : 0;
            if (vid < 0) vid = 0;                 // dummy row: harmless (output guarded)
            int bb = vid >> 18, sp = vid & (R3 - 1);
            int vz = sp >> 12, vy = (sp >> 6) & 63, vx = sp & 63;
            size_t pvox = (size_t)bb * PB + (size_t)(vz + 1) * PS + (size_t)(vy + 1) * P + (vx + 1);
            asrc[i] = xt + pvox * 128 + off;
        }
    }

    int lane = t & 63, w = t >> 6;                // 8 waves; wave tile: 32 voxels x 64 co
    int cl = lane & 15;
    int hi16 = (lane >> 4) * 16;
    int aswz = (cl & 7) << 4;                     // (arow&7)<<4 since w*32+m*16 == 0 mod 8
    int aoff[2][2];
#pragma unroll
    for (int m = 0; m < 2; ++m)
#pragma unroll
        for (int kc = 0; kc < 2; ++kc)
            aoff[m][kc] = (w * 32 + m * 16 + cl) * 128 + ((kc * 64 + hi16) ^ aswz);
    int boff[2][4];
#pragma unroll
    for (int kc = 0; kc < 2; ++kc)
#pragma unroll
        for (int n = 0; n < 4; ++n)
            boff[kc][n] = ((kc * 4 + n) * 64 + lane) * 16;

    f32x4 acc[2][4] = {};

    STAGE(0, 0);                                  // prologue prefetch (5 loads in flight)
#pragma unroll
    for (int tap = 0; tap < 27; ++tap) {
        const int cur = tap & 1;
        // Only this tap's 5 loads are outstanding here; they were issued one
        // full compute phase ago (not a fresh-prefetch drain).
        asm volatile("s_waitcnt vmcnt(0)" ::: "memory");
        asm volatile("s_barrier" ::: "memory");
        // Safe to overwrite buf[cur^1]: every wave's tap-(t-1) ds_reads retired
        // (lgkmcnt(0) below) before it crossed the barrier above.
        if (tap < 26) { STAGE(tap + 1, cur ^ 1); }  // flies under the MFMAs
#pragma unroll
        for (int kc = 0; kc < 2; ++kc) {
            short8 a0 = *(const short8*)&Ab[cur][aoff[0][kc]];
            short8 a1 = *(const short8*)&Ab[cur][aoff[1][kc]];
#pragma unroll
            for (int n = 0; n < 4; ++n) {
                short8 bf = *(const short8*)&Bb[cur][boff[kc][n]];
                acc[0][n] = __builtin_amdgcn_mfma_f32_16x16x32_bf16(a0, bf, acc[0][n], 0, 0, 0);
                acc[1][n] = __builtin_amdgcn_mfma_f32_16x16x32_bf16(a1, bf, acc[1][n], 0, 0, 0);
            }
        }
        asm volatile("s_waitcnt lgkmcnt(0)" ::: "memory");
    }

    // epilogue: D[row=(lane>>4)*4+reg][col=lane&15] (m89-verified layout)
    int q = lane >> 4;
    if (use_compact) {
        // dense compact[idx][64]: full-line coalesced writes
#pragma unroll
        for (int m = 0; m < 2; ++m) {
#pragma unroll
            for (int rg = 0; rg < 4; ++rg) {
                int row = w * 32 + m * 16 + q * 4 + rg;   // 0..255
                int gi = base + row;
                if (gi < count && gi < CAP) {
#pragma unroll
                    for (int n = 0; n < 4; ++n)
                        compact[(size_t)gi * 64 + n * 16 + cl] = acc[m][n][rg];
                }
            }
        }
    } else {
#pragma unroll
        for (int m = 0; m < 2; ++m) {
#pragma unroll
            for (int rg = 0; rg < 4; ++rg) {
                int row = w * 32 + m * 16 + q * 4 + rg;
                int gi = base + row;
                if (gi < count) {
                    int vv = list[gi];
                    int bb2 = vv >> 18;
                    int sp = vv & (R3 - 1);
                    float* op = out + (size_t)(bb2 * 64 + cl) * R3 + sp;
#pragma unroll
                    for (int n = 0; n < 4; ++n)
                        op[(size_t)(n * 16) * R3] = acc[m][n][rg];
                }
            }
        }
    }
}

// ---- pass 3: compact -> dense NCDHW (writes zeros for inactive; replaces memset) ----
// Register transpose: thread t owns voxel vb+t; reads its full 256B compact row
// (every fetched line fully consumed), then 64 coalesced per-co stores.
__global__ void __launch_bounds__(256) finalize(const uint4* __restrict__ compact4,
                                                const int* __restrict__ pos,
                                                float* __restrict__ out) {
    int t = threadIdx.x;
    int vb = blockIdx.x * 256;                // 256 consecutive voxels (never straddle batch)
    int b = vb >> 18;
    int sp0 = vb & (R3 - 1);
    int q = pos[vb + t];
    bool act = (unsigned)q < (unsigned)CAP;
    const uint4* src = compact4 + (size_t)(act ? q : 0) * 16;
    uint4 r[16];
#pragma unroll
    for (int s = 0; s < 16; ++s) {
        uint4 v = {0, 0, 0, 0};
        if (act) v = src[s];
        r[s] = v;
    }
    const float* rf = (const float*)r;
    float* ob = out + (size_t)b * 64 * R3 + sp0 + t;
#pragma unroll
    for (int co = 0; co < 64; ++co)
        ob[(size_t)co * R3] = rf[co];         // co compile-time (rule 20): stays in regs
}

// ---- fallback (ws too small): dense fp32 direct conv, one (b,co,z,y) row per block ----
__global__ void __launch_bounds__(64) fallback_conv(const float* __restrict__ x,
                                                    const float* __restrict__ wt,
                                                    float* __restrict__ out) {
    __shared__ float rowb[66];
    int bid = blockIdx.x;
    int y = bid & 63, z = (bid >> 6) & 63, co = (bid >> 12) & 63, b = bid >> 18;
    int t = threadIdx.x;
    float acc = 0.f;
    bool active = false;
    for (int ci = 0; ci < 64; ++ci) {
        const float* xp = x + ((size_t)(b * 64 + ci)) * R3;
        const float* wp = wt + ((size_t)(co * 64 + ci)) * 27;
        for (int dz = -1; dz <= 1; ++dz) {
            int nz = z + dz;
            bool okz = (unsigned)nz < 64u;
            for (int dy = -1; dy <= 1; ++dy) {
                int ny = y + dy;
                bool ok = okz && ((unsigned)ny < 64u);
                float v = ok ? xp[nz * 4096 + ny * 64 + t] : 0.f;
                rowb[t + 1] = v;
                if (t == 0) { rowb[0] = 0.f; rowb[65] = 0.f; }
                __syncthreads();
                if (dz == 0 && dy == 0) active |= (rowb[t + 1] != 0.f);
                const float* wq = wp + (dz + 1) * 9 + (dy + 1) * 3;
                acc += rowb[t] * wq[0] + rowb[t + 1] * wq[1] + rowb[t + 2] * wq[2];
                __syncthreads();
            }
        }
    }
    out[((size_t)(b * 64 + co)) * R3 + z * 4096 + y * 64 + t] = active ? acc : 0.f;
}

extern "C" void kernel_launch(void* const* d_in, const int* in_sizes, int n_in,
                              void* d_out, int out_size, void* d_ws, size_t ws_size,
                              hipStream_t stream) {
    const float* x = (const float*)d_in[0];
    const float* w = (const float*)d_in[1];
    float* out = (float*)d_out;

    const size_t XT_BYTES = (size_t)4 * PB * 128;             // 147.2 MB padded bf16 channels-last
    const size_t LIST_OFF = XT_BYTES;                         // 4 MB int list
    const size_t POS_OFF  = LIST_OFF + (size_t)NVOX * 4;      // 4 MB int pos
    const size_t WSW_OFF  = POS_OFF + (size_t)NVOX * 4;
    const size_t CNT_OFF  = WSW_OFF + (size_t)WSW_ELEMS * 2;
    const size_t CMP_OFF  = (CNT_OFF + 256 + 255) & ~(size_t)255;
    const size_t NEED_S   = CMP_OFF;                          // scatter path (~156 MB)
    const size_t NEED_C   = CMP_OFF + (size_t)CAP * 64 * 4;   // compact path (~290 MB)

    if (ws_size < NEED_S) {
        fallback_conv<<<NVOX, 64, 0, stream>>>(x, w, out);
        return;
    }

    unsigned int*   xt   = (unsigned int*)d_ws;
    int*            list = (int*)((char*)d_ws + LIST_OFF);
    int*            pos  = (int*)((char*)d_ws + POS_OFF);
    unsigned short* wsw  = (unsigned short*)((char*)d_ws + WSW_OFF);
    int*            cnt  = (int*)((char*)d_ws + CNT_OFF);
    float*          cmp  = (float*)((char*)d_ws + CMP_OFF);
    int use_compact = (ws_size >= NEED_C) ? 1 : 0;

    hipMemsetAsync(cnt, 0, sizeof(int), stream);
    if (!use_compact)
        hipMemsetAsync(d_out, 0, (size_t)out_size * sizeof(float), stream);
    prep_misc<<<(4 * PB + 255) / 256, 256, 0, stream>>>(w, wsw, (uint4*)d_ws);
    xprep<<<NVOX / 256, 256, 0, stream>>>(x, xt, list, pos, cnt);
    sconv_gemm<<<NVOX / 256, 512, 0, stream>>>((const unsigned char*)xt,
                                               (const unsigned char*)wsw, list, cnt,
                                               out, cmp, use_compact);
    if (use_compact)
        finalize<<<NVOX / 256, 256, 0, stream>>>((const uint4*)cmp, pos, out);
}